// Round 5
// baseline (482.328 us; speedup 1.0000x reference)
//
#include <hip/hip_runtime.h>
#include <stdint.h>

// ClassicalHopfield N=8192, P=64.  act_i·N = x_i·m - 64·s_i, m = X^T s (running).
// Blocked (64-neuron) sequential resolve; corrections via 64-bit sign
// signatures (y = s⊙x ∈ {±1}^64):
//   flip i:    ΔT_j = 8·popc(sig_i^sig_j), thr += 256     (= -2·y_j·y_i scaled)
//   block end: m_p += 4·popc(flips & sigT_p) - 2·nf
// T_j = 2·(y_j·m) - (s_j<0), flip ⟺ T_j < thr (thr starts 128). The -(s<0)
// implements act==0 -> +1 exactly. All small integers => exact => bit-identical.
//
// Round-5 changes: (1) Y tiles staged via global_load_lds double-buffer (the
// round-4 register prefetch was silently sunk by the compiler: VGPR=68 < the
// 128 needed, so every block stalled on Y load latency); (2) branchless fully
// unrolled 64-step resolve with immediate-lane readlane and per-16-step group
// skip, replacing the branchy loop (~100cy/flip -> ~18cy/step fixed).

#define NB 128
typedef unsigned long long u64;
typedef unsigned u32;

// ws: m0 f[64] | Ysw f[128*4096] (pre-swizzled, glds-linear layout:
//     [b][j][ (G^(j&7))*4 + c ], p=G*4+c) | sig u64[8192] | sigT u64[8192] |
//     sps f[8192]   ~2.16 MB

__device__ __forceinline__ void glds16(const void* g, void* l) {
  __builtin_amdgcn_global_load_lds(
      (const __attribute__((address_space(1))) void*)g,
      (__attribute__((address_space(3))) void*)l, 16, 0, 0);
}

__global__ __launch_bounds__(256) void hop_prep(
    const float* __restrict__ X, const float* __restrict__ state,
    const int* __restrict__ perm, float* __restrict__ m0,
    float* __restrict__ Ysw, u64* __restrict__ sig, u64* __restrict__ sigT,
    float* __restrict__ sps)
{
  const int b = blockIdx.x, t = threadIdx.x;
  const int wv = t >> 6, ln = t & 63;
  __shared__ u64 sigL[64];
  __shared__ float red[4][64];

  // single X pass: swizzled Y store + row signature + m0 partial
  float acc = 0.f;
  #pragma unroll
  for (int jj = 0; jj < 16; ++jj) {
    const int j = wv*16 + jj;                 // wave-uniform row
    const int r = perm[b*64 + j];
    const float sr = state[r];
    const float x = X[(size_t)r*64 + ln];     // coalesced 256B row
    Ysw[(size_t)b*4096 + j*64 + ((((ln >> 2) ^ (j & 7)) << 2) | (ln & 3))] = x * sr;
    u64 bb = __ballot(x < 0.f);
    if (sr < 0.f) bb = ~bb;                   // sign of y = x*sr
    if (ln == 0) { sig[b*64 + j] = bb; sigL[j] = bb; }
    acc = fmaf(x, sr, acc);
  }
  red[wv][ln] = acc;
  __syncthreads();

  // column signatures: bit i of sigT_p = bit p of sig_i
  {
    const u64 gs = sigL[ln];
    #pragma unroll
    for (int jj = 0; jj < 16; ++jj) {
      const int p = wv*16 + jj;
      u64 tb = __ballot((unsigned)((gs >> p) & 1ull));
      if (ln == 0) sigT[b*64 + p] = tb;
    }
  }

  if (t < 64) {
    atomicAdd(&m0[t], (red[0][t] + red[1][t]) + (red[2][t] + red[3][t]));
    sps[b*64 + t] = state[perm[b*64 + t]];
  }
}

// ---- branchless resolve step machinery ----
// CORE(i): chain = v_cmp -> s_bitcmp1(vcc,i) -> cselects -> v_cndmask.
// SF(i,i+1): readlanes for i+1 issued FIRST (hazard gap), xor/popc after CORE.
#define CORE(I, B, FH) \
  "v_cmp_gt_i32 vcc, %[thr], %[T]\n\t" \
  "v_lshl_add_u32 %[Ts], %[c], 3, %[T]\n\t" \
  "s_bitcmp1_b64 vcc, " I "\n\t" \
  "s_cselect_b64 %[msk], -1, 0\n\t" \
  "s_cselect_b32 %[bt], " B ", 0\n\t" \
  "s_cselect_b32 %[inc], 0x100, 0\n\t" \
  "s_or_b32 %[" FH "], %[" FH "], %[bt]\n\t" \
  "s_add_i32 %[thr], %[thr], %[inc]\n\t" \
  "v_cndmask_b32 %[T], %[T], %[Ts], %[msk]\n\t"

#define SF(I, IN, B, FH) \
  "v_readlane_b32 %[t0], %[slo], " IN "\n\t" \
  "v_readlane_b32 %[t1], %[shi], " IN "\n\t" \
  CORE(I, B, FH) \
  "v_xor_b32 %[x0], %[t0], %[slo]\n\t" \
  "v_xor_b32 %[x1], %[t1], %[shi]\n\t" \
  "v_bcnt_u32_b32 %[c], %[x0], 0\n\t" \
  "v_bcnt_u32_b32 %[c], %[x1], %[c]\n\t"

// group entry: test candidates at positions >= first; skip 16 steps if none.
#define GENT0(FIRST) \
  "v_cmp_gt_i32 vcc, %[thr], %[T]\n\t" \
  "v_readlane_b32 %[t0], %[slo], " FIRST "\n\t" \
  "v_readlane_b32 %[t1], %[shi], " FIRST "\n\t" \
  "s_cmp_lg_u64 vcc, 0\n\t" \
  "s_cbranch_scc0 7f\n\t" \
  "v_xor_b32 %[x0], %[t0], %[slo]\n\t" \
  "v_xor_b32 %[x1], %[t1], %[shi]\n\t" \
  "v_bcnt_u32_b32 %[c], %[x0], 0\n\t" \
  "v_bcnt_u32_b32 %[c], %[x1], %[c]\n\t"

#define GENT(FIRST, SHIFT) \
  "v_cmp_gt_i32 vcc, %[thr], %[T]\n\t" \
  "v_readlane_b32 %[t0], %[slo], " FIRST "\n\t" \
  "v_readlane_b32 %[t1], %[shi], " FIRST "\n\t" \
  "s_lshr_b64 %[msk], vcc, " SHIFT "\n\t" \
  "s_cmp_lg_u64 %[msk], 0\n\t" \
  "s_cbranch_scc0 7f\n\t" \
  "v_xor_b32 %[x0], %[t0], %[slo]\n\t" \
  "v_xor_b32 %[x1], %[t1], %[shi]\n\t" \
  "v_bcnt_u32_b32 %[c], %[x0], 0\n\t" \
  "v_bcnt_u32_b32 %[c], %[x1], %[c]\n\t"

__global__ __launch_bounds__(64) void hop_solve(
    const int* __restrict__ perm, const float* __restrict__ m0,
    const float* __restrict__ Ysw, const u64* __restrict__ sig,
    const u64* __restrict__ sigT, const float* __restrict__ sps,
    float* __restrict__ out)
{
  __shared__ __align__(16) float mlds[64];
  __shared__ __align__(16) float Ybuf[2][4096];
  const int lane = threadIdx.x;   // one wave; lane = row j AND pattern p

  float mreg = m0[lane];
  mlds[lane] = mreg;

  { // stage block 0
    const float* ys = Ysw + lane*4;
    #pragma unroll
    for (int it = 0; it < 16; ++it) glds16(ys + it*256, &Ybuf[0][it*256]);
  }
  u64 sgA = sig[lane], stA = sigT[lane];
  int rA = perm[lane]; float sA = sps[lane];
  asm volatile("s_waitcnt vmcnt(0)" ::: "memory");

  int cur = 0;
  for (int b = 0; b < NB; ++b) {
    u64 sgB = 0, stB = 0; int rB = 0; float sB = 0.f;
    if (b + 1 < NB) {  // async stage next block; cannot be sunk by compiler
      const float* ys = Ysw + (size_t)(b+1)*4096 + lane*4;
      #pragma unroll
      for (int it = 0; it < 16; ++it) glds16(ys + it*256, &Ybuf[cur^1][it*256]);
      sgB = sig[(b+1)*64+lane]; stB = sigT[(b+1)*64+lane];
      rB = perm[(b+1)*64+lane]; sB = sps[(b+1)*64+lane];
    }

    // matvec: q = y_lane · m   (swizzled b128 LDS reads, m broadcast)
    const float* Yc = Ybuf[cur];
    float q0=0.f,q1=0.f,q2=0.f,q3=0.f;
    const float4* mv4 = (const float4*)mlds;
    #pragma unroll
    for (int g = 0; g < 16; ++g) {
      const float4 yv = *(const float4*)&Yc[lane*64 + ((g ^ (lane & 7)) << 2)];
      const float4 mv = mv4[g];
      q0 = fmaf(yv.x, mv.x, q0); q1 = fmaf(yv.y, mv.y, q1);
      q2 = fmaf(yv.z, mv.z, q2); q3 = fmaf(yv.w, mv.w, q3);
    }
    int T = ((int)((q0+q1)+(q2+q3)) << 1) - ((sA < 0.f) ? 1 : 0);

    const u32 slo = (u32)sgA, shi = (u32)(sgA >> 32);
    u32 flo = 0, fhi = 0; int thr = 128;
    u32 t0, t1, x0, x1, c, bt, inc; int Ts; u64 msk;
    asm volatile(
      // ---- group 0: steps 0..15
      GENT0("0")
      SF("0","1","1","flo") SF("1","2","2","flo") SF("2","3","4","flo")
      SF("3","4","8","flo") SF("4","5","0x10","flo") SF("5","6","0x20","flo")
      SF("6","7","0x40","flo") SF("7","8","0x80","flo") SF("8","9","0x100","flo")
      SF("9","10","0x200","flo") SF("10","11","0x400","flo")
      SF("11","12","0x800","flo") SF("12","13","0x1000","flo")
      SF("13","14","0x2000","flo") SF("14","15","0x4000","flo")
      CORE("15","0x8000","flo")
      "7:\n\t"
      // ---- group 1: steps 16..31
      GENT("16","16")
      SF("16","17","0x10000","flo") SF("17","18","0x20000","flo")
      SF("18","19","0x40000","flo") SF("19","20","0x80000","flo")
      SF("20","21","0x100000","flo") SF("21","22","0x200000","flo")
      SF("22","23","0x400000","flo") SF("23","24","0x800000","flo")
      SF("24","25","0x1000000","flo") SF("25","26","0x2000000","flo")
      SF("26","27","0x4000000","flo") SF("27","28","0x8000000","flo")
      SF("28","29","0x10000000","flo") SF("29","30","0x20000000","flo")
      SF("30","31","0x40000000","flo")
      CORE("31","0x80000000","flo")
      "7:\n\t"
      // ---- group 2: steps 32..47
      GENT("32","32")
      SF("32","33","1","fhi") SF("33","34","2","fhi") SF("34","35","4","fhi")
      SF("35","36","8","fhi") SF("36","37","0x10","fhi") SF("37","38","0x20","fhi")
      SF("38","39","0x40","fhi") SF("39","40","0x80","fhi")
      SF("40","41","0x100","fhi") SF("41","42","0x200","fhi")
      SF("42","43","0x400","fhi") SF("43","44","0x800","fhi")
      SF("44","45","0x1000","fhi") SF("45","46","0x2000","fhi")
      SF("46","47","0x4000","fhi")
      CORE("47","0x8000","fhi")
      "7:\n\t"
      // ---- group 3: steps 48..63
      GENT("48","48")
      SF("48","49","0x10000","fhi") SF("49","50","0x20000","fhi")
      SF("50","51","0x40000","fhi") SF("51","52","0x80000","fhi")
      SF("52","53","0x100000","fhi") SF("53","54","0x200000","fhi")
      SF("54","55","0x400000","fhi") SF("55","56","0x800000","fhi")
      SF("56","57","0x1000000","fhi") SF("57","58","0x2000000","fhi")
      SF("58","59","0x4000000","fhi") SF("59","60","0x8000000","fhi")
      SF("60","61","0x10000000","fhi") SF("61","62","0x20000000","fhi")
      SF("62","63","0x40000000","fhi")
      CORE("63","0x80000000","fhi")
      "7:\n\t"
      : [T]"+v"(T), [thr]"+s"(thr), [flo]"+s"(flo), [fhi]"+s"(fhi),
        [t0]"=&s"(t0), [t1]"=&s"(t1), [x0]"=&v"(x0), [x1]"=&v"(x1),
        [c]"=&v"(c), [Ts]"=&v"(Ts), [msk]"=&s"(msk), [bt]"=&s"(bt),
        [inc]"=&s"(inc)
      : [slo]"v"(slo), [shi]"v"(shi)
      : "vcc", "scc");

    const u64 flips = ((u64)fhi << 32) | (u64)flo;
    if (flips) {  // m_p += 4·popc(flips & sigT_p) - 2·nf  (exact ints)
      const int nf = (int)__popcll(flips);
      const int pc = (int)__popcll(flips & stA);
      mreg += (float)(4*pc - 2*nf);
      mlds[lane] = mreg;
    }
    out[rA] = ((flips >> lane) & 1ull) ? -sA : sA;

    // all 16 glds + 4 scalar loads are older than the store: vmcnt(1)
    // guarantees the staged buffer is resident, store may stay in flight.
    asm volatile("s_waitcnt vmcnt(1)" ::: "memory");
    sgA = sgB; stA = stB; rA = rB; sA = sB; cur ^= 1;
  }
}

extern "C" void kernel_launch(void* const* d_in, const int* in_sizes, int n_in,
                              void* d_out, int out_size, void* d_ws, size_t ws_size,
                              hipStream_t stream) {
  const float* X     = (const float*)d_in[0];
  const float* state = (const float*)d_in[1];
  const int*   perm  = (const int*)d_in[2];
  float* outp = (float*)d_out;

  float* m0  = (float*)d_ws;                 // 64 f
  float* Ysw = m0 + 64;                      // 128*4096 f
  u64*   sig = (u64*)(Ysw + 128*4096);       // 8192 u64
  u64*   sigT= sig + 8192;                   // 8192 u64
  float* sps = (float*)(sigT + 8192);        // 8192 f

  hipMemsetAsync(m0, 0, 64*sizeof(float), stream);
  hop_prep<<<dim3(NB), dim3(256), 0, stream>>>(X, state, perm, m0, Ysw, sig, sigT, sps);
  hop_solve<<<dim3(1), dim3(64), 0, stream>>>(perm, m0, Ysw, sig, sigT, sps, outp);
}

// Round 6
// 389.595 us; speedup vs baseline: 1.2380x; 1.2380x over previous
//
#include <hip/hip_runtime.h>
#include <stdint.h>

// ClassicalHopfield N=8192, P=64.  act_i·N = x_i·m - 64·s_i, m = X^T s (running).
// Blocked (64-neuron) sequential resolve; corrections via 64-bit sign
// signatures (y = s⊙x ∈ {±1}^64):
//   flip i:    ΔT_j = 8·popc(sig_i^sig_j), thr += 256     (= -2·y_j·y_i scaled)
//   block end: m_p += 4·popc(flips & sigT_p) - 2·nf
// T_j = 2·(y_j·m) - (s_j<0), flip ⟺ T_j < thr (thr starts 128). The -(s<0)
// implements act==0 -> +1 exactly. All small integers => exact => bit-identical.
//
// Round-6: R5's glds double-buffered LDS matvec (compiler cannot sink it) +
// R4's branchy skip-ahead resolve (flips are dense ~32/block but branchy
// per-FLIP cost beat branchless per-STEP cost empirically), bottom-tested and
// 4x unrolled (1 taken branch per 4 flips), SALU bookkeeping in the readlane
// hazard shadow.

#define NB 128
typedef unsigned long long u64;
typedef unsigned u32;

// ws: m0 f[64] | Ysw f[128*4096] (pre-swizzled, glds-linear layout:
//     [b][j][ (G^(j&7))*4 + c ], p=G*4+c) | sig u64[8192] | sigT u64[8192] |
//     sps f[8192]   ~2.16 MB

__device__ __forceinline__ void glds16(const void* g, void* l) {
  __builtin_amdgcn_global_load_lds(
      (const __attribute__((address_space(1))) void*)g,
      (__attribute__((address_space(3))) void*)l, 16, 0, 0);
}

__global__ __launch_bounds__(256) void hop_prep(
    const float* __restrict__ X, const float* __restrict__ state,
    const int* __restrict__ perm, float* __restrict__ m0,
    float* __restrict__ Ysw, u64* __restrict__ sig, u64* __restrict__ sigT,
    float* __restrict__ sps)
{
  const int b = blockIdx.x, t = threadIdx.x;
  const int wv = t >> 6, ln = t & 63;
  __shared__ u64 sigL[64];
  __shared__ float red[4][64];

  // single X pass: swizzled Y store + row signature + m0 partial
  float acc = 0.f;
  #pragma unroll
  for (int jj = 0; jj < 16; ++jj) {
    const int j = wv*16 + jj;                 // wave-uniform row
    const int r = perm[b*64 + j];
    const float sr = state[r];
    const float x = X[(size_t)r*64 + ln];     // coalesced 256B row
    Ysw[(size_t)b*4096 + j*64 + ((((ln >> 2) ^ (j & 7)) << 2) | (ln & 3))] = x * sr;
    u64 bb = __ballot(x < 0.f);
    if (sr < 0.f) bb = ~bb;                   // sign of y = x*sr
    if (ln == 0) { sig[b*64 + j] = bb; sigL[j] = bb; }
    acc = fmaf(x, sr, acc);
  }
  red[wv][ln] = acc;
  __syncthreads();

  // column signatures: bit i of sigT_p = bit p of sig_i
  {
    const u64 gs = sigL[ln];
    #pragma unroll
    for (int jj = 0; jj < 16; ++jj) {
      const int p = wv*16 + jj;
      u64 tb = __ballot((unsigned)((gs >> p) & 1ull));
      if (ln == 0) sigT[b*64 + p] = tb;
    }
  }

  if (t < 64) {
    atomicAdd(&m0[t], (red[0][t] + red[1][t]) + (red[2][t] + red[3][t]));
    sps[b*64 + t] = state[perm[b*64 + t]];
  }
}

// One resolve step: find first candidate i, flip it, apply correction, re-test.
// Ends with SCC = (more candidates). SALU bookkeeping sits in the readlane
// hazard shadow; chain = ff1 -> readlane -> xor -> bcnt -> bcnt -> lshl_add ->
// v_cmp -> s_and.
#define STEP \
  "s_ff1_i32_b64 %[i], %[mm]\n\t" \
  "v_readlane_b32 %[t0], %[slo], %[i]\n\t" \
  "v_readlane_b32 %[t1], %[shi], %[i]\n\t" \
  "s_lshl_b64 %[bit], 1, %[i]\n\t" \
  "s_or_b64 %[flips], %[flips], %[bit]\n\t" \
  "s_lshl_b64 %[live], -2, %[i]\n\t" \
  "s_addk_i32 %[thr], 0x100\n\t" \
  "v_xor_b32 %[x0], %[t0], %[slo]\n\t" \
  "v_xor_b32 %[x1], %[t1], %[shi]\n\t" \
  "v_bcnt_u32_b32 %[c], %[x0], 0\n\t" \
  "v_bcnt_u32_b32 %[c], %[x1], %[c]\n\t" \
  "v_lshl_add_u32 %[T], %[c], 3, %[T]\n\t" \
  "v_cmp_gt_i32 vcc, %[thr], %[T]\n\t" \
  "s_and_b64 %[mm], vcc, %[live]\n\t"

// Process one 64-neuron block from LDS buffer YB (pre-swizzled).
#define PROCESS(YB, sg, st, rr, ss) {                                         \
  const float* Yc = (YB);                                                     \
  float q0=0.f,q1=0.f,q2=0.f,q3=0.f;                                          \
  const float4* mv4 = (const float4*)mlds;                                    \
  _Pragma("unroll")                                                           \
  for (int g = 0; g < 16; ++g) {                                              \
    const float4 yv = *(const float4*)&Yc[ybase + ((g ^ lswz) << 2)];         \
    const float4 mv = mv4[g];                                                 \
    q0 = fmaf(yv.x, mv.x, q0); q1 = fmaf(yv.y, mv.y, q1);                     \
    q2 = fmaf(yv.z, mv.z, q2); q3 = fmaf(yv.w, mv.w, q3);                     \
  }                                                                           \
  int T = ((int)((q0+q1)+(q2+q3)) << 1) - (((ss) < 0.f) ? 1 : 0);             \
  const u32 slo = (u32)(sg), shi = (u32)((sg) >> 32);                         \
  u64 flips; int thr = 128;                                                   \
  {                                                                           \
    u64 live, mm, bit; u32 i_, t0, t1, x0, x1, c;                             \
    asm volatile(                                                             \
      "s_mov_b64 %[flips], 0\n\t"                                             \
      "s_mov_b64 %[live], -1\n\t"                                             \
      "v_cmp_gt_i32 vcc, %[thr], %[T]\n\t"                                    \
      "s_and_b64 %[mm], vcc, %[live]\n\t"                                     \
      "s_cbranch_scc0 9f\n\t"                                                 \
      "1:\n\t"                                                                \
      STEP "s_cbranch_scc0 9f\n\t"                                            \
      STEP "s_cbranch_scc0 9f\n\t"                                            \
      STEP "s_cbranch_scc0 9f\n\t"                                            \
      STEP "s_cbranch_scc1 1b\n\t"                                            \
      "9:\n\t"                                                                \
      : [flips]"=&s"(flips), [live]"=&s"(live), [mm]"=&s"(mm),                \
        [bit]"=&s"(bit), [i]"=&s"(i_), [t0]"=&s"(t0), [t1]"=&s"(t1),          \
        [thr]"+s"(thr), [T]"+v"(T), [x0]"=&v"(x0), [x1]"=&v"(x1),             \
        [c]"=&v"(c)                                                           \
      : [slo]"v"(slo), [shi]"v"(shi)                                          \
      : "vcc", "scc");                                                        \
  }                                                                           \
  if (flips) {  /* m_p += 4·popc(flips & sigT_p) - 2·nf  (exact ints) */      \
    const int nf = (int)__popcll(flips);                                      \
    const int pc = (int)__popcll(flips & (st));                               \
    mreg += (float)(4*pc - 2*nf);                                             \
    mlds[lane] = mreg;                                                        \
  }                                                                           \
  out[rr] = ((flips >> lane) & 1ull) ? -(ss) : (ss);                          \
}

#define PREFETCH(BN, BUF, sg, st, rr, ss) {                                   \
  const float* ys = Ysw + (size_t)(BN)*4096 + lane*4;                         \
  _Pragma("unroll")                                                           \
  for (int it = 0; it < 16; ++it) glds16(ys + it*256, &(BUF)[it*256]);        \
  sg = sig[(BN)*64+lane]; st = sigT[(BN)*64+lane];                            \
  rr = perm[(BN)*64+lane]; ss = sps[(BN)*64+lane];                            \
}

__global__ __launch_bounds__(64) void hop_solve(
    const int* __restrict__ perm, const float* __restrict__ m0,
    const float* __restrict__ Ysw, const u64* __restrict__ sig,
    const u64* __restrict__ sigT, const float* __restrict__ sps,
    float* __restrict__ out)
{
  __shared__ __align__(16) float mlds[64];
  __shared__ __align__(16) float Ybuf[2][4096];
  const int lane = threadIdx.x;   // one wave; lane = row j AND pattern p
  const int ybase = lane*64, lswz = lane & 7;

  float mreg = m0[lane];
  mlds[lane] = mreg;

  u64 sgA, stA, sgB, stB; int rA, rB; float sA, sB;
  PREFETCH(0, Ybuf[0], sgA, stA, rA, sA);
  asm volatile("s_waitcnt vmcnt(0)" ::: "memory");

  for (int bb = 0; bb < NB; bb += 2) {
    PREFETCH(bb+1, Ybuf[1], sgB, stB, rB, sB);         // async, fills buf1
    PROCESS(Ybuf[0], sgA, stA, rA, sA);
    // glds(buf1) + scalar loads older than out-store: vmcnt(1) => buf1 ready
    asm volatile("s_waitcnt vmcnt(1)" ::: "memory");
    if (bb + 2 < NB) PREFETCH(bb+2, Ybuf[0], sgA, stA, rA, sA);
    PROCESS(Ybuf[1], sgB, stB, rB, sB);
    asm volatile("s_waitcnt vmcnt(1)" ::: "memory");
  }
}

extern "C" void kernel_launch(void* const* d_in, const int* in_sizes, int n_in,
                              void* d_out, int out_size, void* d_ws, size_t ws_size,
                              hipStream_t stream) {
  const float* X     = (const float*)d_in[0];
  const float* state = (const float*)d_in[1];
  const int*   perm  = (const int*)d_in[2];
  float* outp = (float*)d_out;

  float* m0  = (float*)d_ws;                 // 64 f
  float* Ysw = m0 + 64;                      // 128*4096 f
  u64*   sig = (u64*)(Ysw + 128*4096);       // 8192 u64
  u64*   sigT= sig + 8192;                   // 8192 u64
  float* sps = (float*)(sigT + 8192);        // 8192 f

  hipMemsetAsync(m0, 0, 64*sizeof(float), stream);
  hop_prep<<<dim3(NB), dim3(256), 0, stream>>>(X, state, perm, m0, Ysw, sig, sigT, sps);
  hop_solve<<<dim3(1), dim3(64), 0, stream>>>(perm, m0, Ysw, sig, sigT, sps, outp);
}